// Round 4
// baseline (246.136 us; speedup 1.0000x reference)
//
#include <hip/hip_runtime.h>

#define TOKENS 4096
#define HDIM   1024
#define EDIM   8
#define CAP    1536
#define TAU    0.10f

typedef float f32x4 __attribute__((ext_vector_type(4)));
typedef short bf16x8 __attribute__((ext_vector_type(8)));

static __device__ __forceinline__ unsigned short f2bf(float f) {
    unsigned int u = __float_as_uint(f);
    return (unsigned short)((u + 0x7fffu + ((u >> 16) & 1u)) >> 16);  // RNE
}

// ---------------- GEMM1 (bf16 MFMA) fused with 402MB zero-fill ----------------
// h = relu(X @ W1 + b1), X:(4096,1024) W1:(1024,1024), tiles 128x128, BK=32.
// A stored [m][k], B stored [n][k] (both k-contiguous, pad 40): identical
// (lane-group -> k) indexing for A and B frags => any HW k-permutation cancels.
#define ZF4_PER_BLOCK 98304   // 402653184 B / 256 blocks / 16 B

__global__ __launch_bounds__(256, 2) void gemm1_mfma_fill(
    const float* __restrict__ X, const float* __restrict__ W1,
    const float* __restrict__ b1, float* __restrict__ Hout,
    float* __restrict__ zfill)
{
    __shared__ unsigned short As[128][40];   // 40 ushort = 80 B row (16B-aligned, ~2-4 way banks)
    __shared__ unsigned short Bs[128][40];
    const int tid  = threadIdx.x;
    const int wave = tid >> 6, lane = tid & 63;
    const int wm = (wave >> 1) * 64, wn = (wave & 1) * 64;
    const int g = lane >> 4, r = lane & 15;
    const int m0 = blockIdx.y * 128, n0 = blockIdx.x * 128;

    const int srow = tid >> 1;           // A staging: row 0..127
    const int soff = (tid & 1) * 16;     // k-offset 0/16
    const int bn   = tid & 127;          // B staging: col (consecutive lanes -> coalesced)
    const int bko  = (tid >> 7) * 16;    // k-offset 0/16

    const int blk = blockIdx.y * 8 + blockIdx.x;     // 0..255
    f32x4* Z = (f32x4*)zfill + (size_t)blk * ZF4_PER_BLOCK + tid;
    const f32x4 z4 = {0.f, 0.f, 0.f, 0.f};

    f32x4 acc[4][4] = {};
    int zs = 0;
    for (int k0 = 0; k0 < HDIM; k0 += 32) {
        // ---- stage A: 16 f32 -> 16 bf16, two b128 LDS writes
        const float* ap = X + (size_t)(m0 + srow) * HDIM + k0 + soff;
        float4 a0 = *(const float4*)(ap);
        float4 a1 = *(const float4*)(ap + 4);
        float4 a2 = *(const float4*)(ap + 8);
        float4 a3 = *(const float4*)(ap + 12);
        uint4 w0, w1;
        w0.x = f2bf(a0.x) | ((unsigned)f2bf(a0.y) << 16);
        w0.y = f2bf(a0.z) | ((unsigned)f2bf(a0.w) << 16);
        w0.z = f2bf(a1.x) | ((unsigned)f2bf(a1.y) << 16);
        w0.w = f2bf(a1.z) | ((unsigned)f2bf(a1.w) << 16);
        w1.x = f2bf(a2.x) | ((unsigned)f2bf(a2.y) << 16);
        w1.y = f2bf(a2.z) | ((unsigned)f2bf(a2.w) << 16);
        w1.z = f2bf(a3.x) | ((unsigned)f2bf(a3.y) << 16);
        w1.w = f2bf(a3.z) | ((unsigned)f2bf(a3.w) << 16);
        *(uint4*)&As[srow][soff]     = w0;
        *(uint4*)&As[srow][soff + 8] = w1;

        // ---- stage B transposed: 16 k-strided dword loads (lane-coalesced), two b128 writes
        const float* bp = W1 + (size_t)(k0 + bko) * HDIM + n0 + bn;
        float bv[16];
#pragma unroll
        for (int j = 0; j < 16; j++) bv[j] = bp[(size_t)j * HDIM];
        uint4 q0, q1;
        q0.x = f2bf(bv[0])  | ((unsigned)f2bf(bv[1])  << 16);
        q0.y = f2bf(bv[2])  | ((unsigned)f2bf(bv[3])  << 16);
        q0.z = f2bf(bv[4])  | ((unsigned)f2bf(bv[5])  << 16);
        q0.w = f2bf(bv[6])  | ((unsigned)f2bf(bv[7])  << 16);
        q1.x = f2bf(bv[8])  | ((unsigned)f2bf(bv[9])  << 16);
        q1.y = f2bf(bv[10]) | ((unsigned)f2bf(bv[11]) << 16);
        q1.z = f2bf(bv[12]) | ((unsigned)f2bf(bv[13]) << 16);
        q1.w = f2bf(bv[14]) | ((unsigned)f2bf(bv[15]) << 16);
        *(uint4*)&Bs[bn][bko]     = q0;
        *(uint4*)&Bs[bn][bko + 8] = q1;

        // ---- 12 nontemporal zero-stores (fill rides the vmem pipe)
#pragma unroll
        for (int s = 0; s < 12; s++)
            __builtin_nontemporal_store(z4, Z + (size_t)(zs + s) * 256);
        zs += 12;

        __syncthreads();
        bf16x8 af[4], bfr[4];
#pragma unroll
        for (int i = 0; i < 4; i++) {
            af[i]  = *(const bf16x8*)&As[wm + i * 16 + r][g * 8];
            bfr[i] = *(const bf16x8*)&Bs[wn + i * 16 + r][g * 8];
        }
#pragma unroll
        for (int i = 0; i < 4; i++)
#pragma unroll
            for (int j = 0; j < 4; j++)
                acc[i][j] = __builtin_amdgcn_mfma_f32_16x16x32_bf16(af[i], bfr[j], acc[i][j], 0, 0, 0);
        __syncthreads();
    }

    // epilogue: D col = lane&15, row = (lane>>4)*4 + reg  [m89-verified]
#pragma unroll
    for (int j = 0; j < 4; j++) {
        const int col = n0 + wn + j * 16 + r;
        const float bias = b1[col];
#pragma unroll
        for (int i = 0; i < 4; i++) {
            const int row = m0 + wm + i * 16 + g * 4;
#pragma unroll
            for (int q = 0; q < 4; q++)
                Hout[(size_t)(row + q) * HDIM + col] = fmaxf(acc[i][j][q] + bias, 0.f);
        }
    }
}

// ---------------- Router pass (mode 0: all tokens, flag risky; mode 1: rescued only) ----------------
__global__ __launch_bounds__(256) void router_pass(
    const float* __restrict__ Hbuf, const float* __restrict__ W2,
    const float* __restrict__ b2, float* __restrict__ probs_out,
    int* __restrict__ e0a, int* __restrict__ e1a,
    float* __restrict__ p0a, float* __restrict__ p1a,
    int* __restrict__ flags, int* __restrict__ nf, int* __restrict__ list,
    int mode)
{
    const int wave = threadIdx.x >> 6;
    const int lane = threadIdx.x & 63;
    const int idx  = blockIdx.x * 4 + wave;
    int token = idx;
    if (mode == 1) {
        if (idx >= nf[0]) return;
        token = list[idx];
    }

    const float* hrow = Hbuf + (size_t)token * HDIM;
    float acc[8] = {0, 0, 0, 0, 0, 0, 0, 0};
#pragma unroll
    for (int k = 0; k < HDIM / 64; k++) {
        const int hidx = lane + (k << 6);
        const float hv = hrow[hidx];
        float4 wa = *(const float4*)(W2 + hidx * 8);
        float4 wb = *(const float4*)(W2 + hidx * 8 + 4);
        acc[0] = fmaf(hv, wa.x, acc[0]);
        acc[1] = fmaf(hv, wa.y, acc[1]);
        acc[2] = fmaf(hv, wa.z, acc[2]);
        acc[3] = fmaf(hv, wa.w, acc[3]);
        acc[4] = fmaf(hv, wb.x, acc[4]);
        acc[5] = fmaf(hv, wb.y, acc[5]);
        acc[6] = fmaf(hv, wb.z, acc[6]);
        acc[7] = fmaf(hv, wb.w, acc[7]);
    }
#pragma unroll
    for (int off = 32; off; off >>= 1)
#pragma unroll
        for (int e = 0; e < 8; e++) acc[e] += __shfl_xor(acc[e], off);

    if (lane == 0) {
        float logit[8];
#pragma unroll
        for (int e = 0; e < 8; e++) logit[e] = acc[e] + b2[e];
        // top-3 (strict > => ties to lower index, matches lax.top_k)
        int e0 = 0; float m0 = logit[0];
#pragma unroll
        for (int e = 1; e < 8; e++) if (logit[e] > m0) { m0 = logit[e]; e0 = e; }
        int e1 = -1; float m1 = -1e30f;
#pragma unroll
        for (int e = 0; e < 8; e++) if (e != e0 && logit[e] > m1) { m1 = logit[e]; e1 = e; }
        float m2 = -1e30f;
#pragma unroll
        for (int e = 0; e < 8; e++) if (e != e0 && e != e1 && logit[e] > m2) m2 = logit[e];

        if (mode == 0 && ((m0 - m1 < TAU) || (m1 - m2 < TAU))) {
            int w = atomicAdd(nf, 1);
            list[w] = token;            // defer to exact recompute
        } else {
            float mx = m0, p[8], s = 0.f;
#pragma unroll
            for (int e = 0; e < 8; e++) { p[e] = expf(logit[e] - mx); s += p[e]; }
            const float inv = 1.f / s;
#pragma unroll
            for (int e = 0; e < 8; e++) p[e] *= inv;
            float4 pa = {p[0], p[1], p[2], p[3]};
            float4 pb = {p[4], p[5], p[6], p[7]};
            *(float4*)(probs_out + (size_t)token * 8)     = pa;
            *(float4*)(probs_out + (size_t)token * 8 + 4) = pb;
            const float ps = p[e0] + p[e1];
            e0a[token] = e0;
            e1a[token] = e1;
            p0a[token] = p[e0] / ps;
            p1a[token] = p[e1] / ps;
            atomicOr(&flags[e0], 1);
        }
    }
}

// ---------------- exact fp32 recompute of h-rows for flagged tokens ----------------
__global__ __launch_bounds__(256) void rescue_gemm(
    const float* __restrict__ X, const float* __restrict__ W1,
    const float* __restrict__ b1, float* __restrict__ Hout,
    const int* __restrict__ nf, const int* __restrict__ list)
{
    const int n  = nf[0];
    const int i0 = blockIdx.y * 32;
    if (i0 >= n) return;
    const int c0 = blockIdx.x * 128;

    __shared__ float Xs[32][36];    // 144 B rows (16B-aligned)
    __shared__ float Ws[32][132];   // 528 B rows (16B-aligned)
    __shared__ int   toks[32];
    const int tid = threadIdx.x;
    if (tid < 32) toks[tid] = (i0 + tid < n) ? list[i0 + tid] : list[n - 1]; // clamp: dup writes same value
    __syncthreads();

    const int xi = tid >> 3;            // 0..31 token-row for X staging
    const int kq = (tid & 7) * 4;       // k quad
    const int wk = tid >> 3;            // 0..31 k-row for W staging
    const int cq = (tid & 7) * 16;      // col offset
    const int to4 = (tid >> 5) * 4;     // 4 tokens per thread
    const int co4 = (tid & 31) * 4;     // 4 cols per thread

    float acc[4][4] = {};
    for (int k0 = 0; k0 < HDIM; k0 += 32) {
        *(float4*)&Xs[xi][kq] = *(const float4*)(X + (size_t)toks[xi] * HDIM + k0 + kq);
        const float* wp = W1 + (size_t)(k0 + wk) * HDIM + c0 + cq;
        *(float4*)&Ws[wk][cq]      = *(const float4*)(wp);
        *(float4*)&Ws[wk][cq + 4]  = *(const float4*)(wp + 4);
        *(float4*)&Ws[wk][cq + 8]  = *(const float4*)(wp + 8);
        *(float4*)&Ws[wk][cq + 12] = *(const float4*)(wp + 12);
        __syncthreads();
#pragma unroll
        for (int kk = 0; kk < 32; kk++) {
            float4 wv = *(const float4*)&Ws[kk][co4];
            float xv[4];
#pragma unroll
            for (int t = 0; t < 4; t++) xv[t] = Xs[to4 + t][kk];
#pragma unroll
            for (int t = 0; t < 4; t++) {
                acc[t][0] = fmaf(xv[t], wv.x, acc[t][0]);
                acc[t][1] = fmaf(xv[t], wv.y, acc[t][1]);
                acc[t][2] = fmaf(xv[t], wv.z, acc[t][2]);
                acc[t][3] = fmaf(xv[t], wv.w, acc[t][3]);
            }
        }
        __syncthreads();
    }
#pragma unroll
    for (int t = 0; t < 4; t++) {
        const size_t row = (size_t)toks[to4 + t] * HDIM;
#pragma unroll
        for (int c = 0; c < 4; c++) {
            const int col = c0 + co4 + c;
            Hout[row + col] = fmaxf(acc[t][c] + b1[col], 0.f);
        }
    }
}

// ---------------- scatter dispatch/combine + aux loss (block 0) ----------------
__global__ __launch_bounds__(256) void scatter_aux_k(
    const int* __restrict__ e0a, const int* __restrict__ e1a,
    const float* __restrict__ p0a, const float* __restrict__ p1a,
    const int* __restrict__ flags,
    float* __restrict__ dispatch, float* __restrict__ combine,
    const float* __restrict__ probs, float* __restrict__ auxout)
{
    const int t = blockIdx.x * 256 + threadIdx.x;
    if (t < TOKENS) {
        const int e0 = e0a[t], e1 = e1a[t];
        const size_t b0 = ((size_t)t * EDIM + e0) * CAP;   // round-0 pick -> slot 0
        dispatch[b0] = 1.f;
        combine[b0]  = p0a[t];
        const int s1 = flags[e1] ? 1 : 0;                  // slot 1 iff e1 was anyone's round-0 pick
        const size_t b1 = ((size_t)t * EDIM + e1) * CAP + s1;
        dispatch[b1] = 1.f;
        combine[b1]  = p1a[t];
    }

    if (blockIdx.x == 0) {
        __shared__ float red[4][8];
        const int tid = threadIdx.x, lane = tid & 63, wave = tid >> 6;
        float acc[8] = {0, 0, 0, 0, 0, 0, 0, 0};
        for (int tt = tid; tt < TOKENS; tt += 256) {
            float4 a = *(const float4*)(probs + (size_t)tt * 8);
            float4 b = *(const float4*)(probs + (size_t)tt * 8 + 4);
            acc[0] += a.x; acc[1] += a.y; acc[2] += a.z; acc[3] += a.w;
            acc[4] += b.x; acc[5] += b.y; acc[6] += b.z; acc[7] += b.w;
        }
#pragma unroll
        for (int off = 32; off; off >>= 1)
#pragma unroll
            for (int e = 0; e < 8; e++) acc[e] += __shfl_xor(acc[e], off);
        if (lane == 0)
#pragma unroll
            for (int e = 0; e < 8; e++) red[wave][e] = acc[e];
        __syncthreads();
        if (tid == 0) {
            float aux = 0.f;
#pragma unroll
            for (int e = 0; e < 8; e++) {
                float pe = (red[0][e] + red[1][e] + red[2][e] + red[3][e]) * (1.f / TOKENS);
                aux += pe * logf(pe * (float)EDIM + 1e-9f);
            }
            *auxout = aux;
        }
    }
}

extern "C" void kernel_launch(void* const* d_in, const int* in_sizes, int n_in,
                              void* d_out, int out_size, void* d_ws, size_t ws_size,
                              hipStream_t stream)
{
    const float* X  = (const float*)d_in[0];
    const float* W1 = (const float*)d_in[1];
    const float* b1 = (const float*)d_in[2];
    const float* W2 = (const float*)d_in[3];
    const float* b2 = (const float*)d_in[4];

    float* out = (float*)d_out;
    const size_t dispN = (size_t)TOKENS * EDIM * CAP;   // 50,331,648
    float* dispatch = out;
    float* combine  = out + dispN;
    float* probs    = out + 2 * dispN;
    float* auxout   = out + 2 * dispN + (size_t)TOKENS * EDIM;

    float* hbuf = (float*)d_ws;
    char* pp = (char*)d_ws + (size_t)TOKENS * HDIM * sizeof(float);
    int*   e0a  = (int*)pp;   pp += TOKENS * sizeof(int);
    int*   e1a  = (int*)pp;   pp += TOKENS * sizeof(int);
    float* p0a  = (float*)pp; pp += TOKENS * sizeof(float);
    float* p1a  = (float*)pp; pp += TOKENS * sizeof(float);
    int*   flags = (int*)pp;  pp += EDIM * sizeof(int);
    int*   nf    = (int*)pp;  pp += sizeof(int);
    int*   list  = (int*)pp;

    hipMemsetAsync(flags, 0, (EDIM + 1) * sizeof(int), stream);   // flags + nf

    gemm1_mfma_fill<<<dim3(8, 32), 256, 0, stream>>>(X, W1, b1, hbuf, dispatch);
    router_pass<<<TOKENS / 4, 256, 0, stream>>>(hbuf, W2, b2, probs,
                                                e0a, e1a, p0a, p1a, flags, nf, list, 0);
    rescue_gemm<<<dim3(8, 128), 256, 0, stream>>>(X, W1, b1, hbuf, nf, list);
    router_pass<<<TOKENS / 4, 256, 0, stream>>>(hbuf, W2, b2, probs,
                                                e0a, e1a, p0a, p1a, flags, nf, list, 1);
    scatter_aux_k<<<TOKENS / 256, 256, 0, stream>>>(
        e0a, e1a, p0a, p1a, flags, dispatch, combine, probs, auxout);
}